// Round 4
// baseline (1609.442 us; speedup 1.0000x reference)
//
#include <hip/hip_runtime.h>

typedef unsigned short u16;
typedef short s16x8 __attribute__((ext_vector_type(8)));   // 8 bf16 bit-patterns
typedef float f32x4 __attribute__((ext_vector_type(4)));

#define DI __device__ __forceinline__

constexpr int N_ = 50000;
constexpr int E_ = 400000;
constexpr int G_ = 64;
constexpr int MS_ = 112;            // msg row stride in u16 (224 B)

DI u16 f2bf(float f) {
    union { unsigned u; float f; } c; c.f = f;
    unsigned u = c.u;
    u += 0x7fffu + ((u >> 16) & 1u);   // RNE
    return (u16)(u >> 16);
}
DI float bf2f(u16 v) {
    union { unsigned u; float f; } c; c.u = (unsigned)v << 16;
    return c.f;
}

DI s16x8 ldv(const u16* p) { return *(const s16x8*)p; }
DI f32x4 MFMA(s16x8 a, s16x8 b, f32x4 c) {
    return __builtin_amdgcn_mfma_f32_16x16x32_bf16(a, b, c, 0, 0, 0);
}

// async global->LDS, 16 B per lane. LDS dest is wave-uniform base + lane*16
// (m104/m108); global src is per-lane. Our weight tiles are linear so the
// linear-dest constraint is free.
DI void stage16(const u16* g, u16* l) {
    __builtin_amdgcn_global_load_lds(
        (__attribute__((address_space(1))) void*)(u16*)g,
        (__attribute__((address_space(3))) void*)l, 16, 0, 0);
}
// cooperative copy of `bytes` (multiple of 1024) from global to LDS.
// wave-uniform lds offset; per-lane global offset.
DI void stage_run(const u16* g, u16* l, int bytes, int wave, int lane) {
    for (int off = wave * 1024; off < bytes; off += 4096)
        stage16(g + (off >> 1) + lane * 8, l + (off >> 1));
}

// ---------------------------------------------------------------------------
// Named kernel (symbol required by harness): zero hist (200 KB) and repack
// weights f32 -> bf16 in MFMA-FRAGMENT-ORDER TILES, folding
//   [xi, xj-xi] @ W = xi @ (W_a - W_b) + xj @ W_b.
// ---------------------------------------------------------------------------
__global__ __launch_bounds__(256)
void ModelGNN_35304631174019_kernel(
          const float* __restrict__ l0w1, const float* __restrict__ l0w2,
          const float* __restrict__ l0w3, const float* __restrict__ l1w1,
          const float* __restrict__ l1w2, const float* __restrict__ l1w3,
          float4* __restrict__ histz,
          u16* __restrict__ wt0, u16* __restrict__ wt1,
          u16* __restrict__ wt2a, u16* __restrict__ wt2b,
          u16* __restrict__ wt3a, u16* __restrict__ wt3b)
{
    int i = blockIdx.x * 256 + threadIdx.x;
    if (i < 12500) { histz[i] = make_float4(0.f, 0.f, 0.f, 0.f); return; }
    int f = i - 12500;

    if (f < 10240) {                       // wt0: layer0 W1, KP=32 (KA=1)
        int sec = f >> 9, w = f & 511;
        int col = w >> 5, rem = w & 31;
        int n0c = sec >> 1, b01 = sec & 1;
        int n = n0c * 32 + b01 * 16 + col, k = rem;
        u16 v = 0;
        if (n < 300) {
            if (k < 7) v = f2bf(l0w1[k * 300 + n] - l0w1[(7 + k) * 300 + n]);
            else if (k >= 16 && k < 23) v = f2bf(l0w1[(7 + (k - 16)) * 300 + n]);
        }
        wt0[f] = v; return;
    }
    f -= 10240;
    if (f < 71680) {                       // wt1: layer1 W1, KP=224 (KA=7)
        int sec = f >> 9, w = f & 511;
        int col = w >> 5, rem = w & 31;
        int n0c = sec / 14, r = sec % 14;
        int s = r >> 1, b01 = r & 1;
        int n = n0c * 32 + b01 * 16 + col, k = s * 32 + rem;
        u16 v = 0;
        if (n < 300) {
            if (k < 100) v = f2bf(l1w1[k * 300 + n] - l1w1[(100 + k) * 300 + n]);
            else if (k >= 112 && k < 212) v = f2bf(l1w1[(100 + (k - 112)) * 300 + n]);
        }
        wt1[f] = v; return;
    }
    f -= 71680;
    if (f < 204800) {                      // wt2a / wt2b: 300x300, K=320 (KA=10)
        const float* src = (f < 102400) ? l0w2 : l1w2;
        u16* dst = (f < 102400) ? wt2a : wt2b;
        int f2 = (f < 102400) ? f : f - 102400;
        int sec = f2 >> 9, w = f2 & 511;
        int col = w >> 5, rem = w & 31;
        int n0c = sec / 20, r = sec % 20;
        int s = r >> 1, b01 = r & 1;
        int n = n0c * 32 + b01 * 16 + col, k = s * 32 + rem;
        dst[f2] = (n < 300 && k < 300) ? f2bf(src[k * 300 + n]) : (u16)0;
        return;
    }
    f -= 204800;
    if (f < 71680) {                       // wt3a / wt3b: 300x100 -> [112 n3][320 k]
        const float* src = (f < 35840) ? l0w3 : l1w3;
        u16* dst = (f < 35840) ? wt3a : wt3b;
        int f2 = (f < 35840) ? f : f - 35840;
        int sec = f2 >> 9, w = f2 & 511;
        int col = w >> 5, rem = w & 31;
        int ch = sec / 7, u = sec % 7;
        int n3 = u * 16 + col, k = ch * 32 + rem;
        dst[f2] = (n3 < 100 && k < 300) ? f2bf(src[k * 100 + n3]) : (u16)0;
        return;
    }
}

// ---------------------------------------------------------------------------
// Count-sort edges by dst: hist -> exclusive scan -> scatter-fill.
// pos[d] = run END after fill (start = pos[d-1] or 0) -- used by reduce_k.
// ---------------------------------------------------------------------------
__global__ __launch_bounds__(256)
void hist_k(const int* __restrict__ ei, int* __restrict__ hist)
{
    int i = blockIdx.x * 256 + threadIdx.x;
    if (i < E_) atomicAdd(&hist[ei[E_ + i]], 1);
}

__global__ __launch_bounds__(1024)
void scan_k(int* h)   // in-place exclusive scan of h[50000], single block
{
    __shared__ int part[1024];
    const int t = threadIdx.x;
    const int CH = 49;
    int base = t * CH;
    int end = base + CH; if (end > 50000) end = 50000;
    int s = 0;
    for (int i = base; i < end; ++i) s += h[i];
    part[t] = s;
    __syncthreads();
    for (int d = 1; d < 1024; d <<= 1) {
        int v = (t >= d) ? part[t - d] : 0;
        __syncthreads();
        part[t] += v;
        __syncthreads();
    }
    int run = (t ? part[t - 1] : 0);
    for (int i = base; i < end; ++i) { int c = h[i]; h[i] = run; run += c; }
}

__global__ __launch_bounds__(256)
void fill_k(const int* __restrict__ ei, int* __restrict__ pos, int* __restrict__ sei)
{
    int i = blockIdx.x * 256 + threadIdx.x;
    if (i >= E_) return;
    int s = ei[i], d = ei[E_ + i];
    int p = atomicAdd(&pos[d], 1);
    sei[p] = s; sei[E_ + p] = d;
}

// ---------------------------------------------------------------------------
// edge_mlp R14: block-cooperative DOUBLE-BUFFERED LDS weight staging.
// R0-R3 held at 530-640us regardless of scatter mechanism -> the bound is
// the per-wave serial chunk chain {global weight loads -> wait -> MFMA ->
// LDS transit} x30 with ~2 waves/SIMD (measured ~5800 cyc/chunk). Fix =
// m97/S5 structure: all 4 waves share one weight stream; stage chunk t+1
// into LDS slot[(t+1)&1] via global_load_lds(16B) WHILE computing chunk t
// from slot[t&1]; one __syncthreads (vmcnt+lgkm drain) per chunk.
// Weight L2 traffic /4; load latency hidden under 28-54 MFMA per chunk.
// Msg epilogue: repack through freed weight-LDS to row-major [32][112] u16,
// then flat LDS->global copy (7x fully-coalesced 1KB stores/wave) -- kills
// the 4x write amplification of 2B scattered stores (R3: 328MB for 80MB).
// Layouts (m89/m120): A: m=lane&15,k=quad*8+j ; B: n=lane&15,k=quad*8+j ;
// C/D: col=lane&15, row=quad*4+reg.
// ---------------------------------------------------------------------------
template<bool FIRST>
__global__ __launch_bounds__(256, 2)
void edge_mlp(const float* __restrict__ X, const float* __restrict__ H0,
              const int* __restrict__ ei,
              const u16* __restrict__ W1, const float* __restrict__ B1,
              const u16* __restrict__ W2, const float* __restrict__ B2,
              const u16* __restrict__ W3, const float* __restrict__ B3,
              u16* __restrict__ msg)
{
    constexpr int KA = FIRST ? 1 : 7;          // K-sections per GEMM1 chunk
    // LDS: 2 weight slots of 14336 u16 (28672 B) + 4 wave-private transits.
    // slot layout: G1 chunk: sections 0..2*KA-1 | G2 chunk: W2 sec 0..19 at 0,
    // W3 sec 0..6 at u16 offset 10240.
    __shared__ __align__(16) u16 WLDS[2 * 14336];     // 57,344 B
    __shared__ __align__(16) u16 SCR[4 * 32 * 40];    // 10,240 B

    const int tid  = threadIdx.x;
    const int wave = tid >> 6, lane = tid & 63;
    const int col  = lane & 15, kq = lane >> 4;
    const int ebase = blockIdx.x * 128 + wave * 32;   // 32 edges per wave
    const int fragoff = col * 32 + kq * 8;            // in-section lane offset

    u16* SCw = SCR + wave * (32 * 40);

    // ---- prologue staging ----
    if constexpr (FIRST) {
        stage_run(W1, WLDS, 20480, wave, lane);               // ALL of wt0 -> slot0
        stage_run(W2, WLDS + 14336, 20480, wave, lane);       // G2 c0 -> slot1
        stage_run(W3, WLDS + 14336 + 10240, 7168, wave, lane);
    } else {
        stage_run(W1, WLDS, 14336, wave, lane);               // G1 c0 -> slot0
    }

    // ---- A fragments ----
    s16x8 aF[2][KA];
    if constexpr (FIRST) {
        // gather [xi | xj] for 32 edges into SCw as bf16 IN[32][40] (K pad 32)
        for (int s = lane; s < 32 * 32; s += 64) {
            int e = s >> 5, k = s & 31;
            u16 v = 0;
            if (k < 7)                  v = f2bf(X[(size_t)ei[E_ + ebase + e] * 7 + k]);
            else if (k >= 16 && k < 23) v = f2bf(X[(size_t)ei[ebase + e] * 7 + (k - 16)]);
            SCw[e * 40 + k] = v;
        }
        #pragma unroll
        for (int rt = 0; rt < 2; ++rt)
            aF[rt][0] = ldv(SCw + (rt * 16 + col) * 40 + kq * 8);
    } else {
        // build A-fragments from global agg0 (h0, f32 -> bf16), 2 row-tiles
        #pragma unroll
        for (int rt = 0; rt < 2; ++rt) {
            const int dn = ei[E_ + ebase + rt * 16 + col];   // x_i
            const int sn = ei[ebase + rt * 16 + col];        // x_j
            #pragma unroll
            for (int s = 0; s < KA; ++s) {
                int b = s * 4 + kq;                // 8-elem k-group, 0..27; k = 8b+j
                int node = (b < 14) ? dn : sn;
                int c = ((b < 14) ? b : b - 14) * 8;
                s16x8 t = {0, 0, 0, 0, 0, 0, 0, 0};
                if (c < 104) {
                    const float* r = H0 + (size_t)node * 100 + c;
                    float4 lo = *(const float4*)r;
                    t[0] = (short)f2bf(lo.x); t[1] = (short)f2bf(lo.y);
                    t[2] = (short)f2bf(lo.z); t[3] = (short)f2bf(lo.w);
                    if (c < 96) {
                        float4 hi = *(const float4*)(r + 4);
                        t[4] = (short)f2bf(hi.x); t[5] = (short)f2bf(hi.y);
                        t[6] = (short)f2bf(hi.z); t[7] = (short)f2bf(hi.w);
                    }
                }
                aF[rt][s] = t;
            }
        }
    }

    __syncthreads();   // prologue staging landed (vmcnt+lgkm drain)

    // ---- GEMM1: [32,KP] x Wt1 -> per-chunk H1 transit -> a2 fragments ----
    s16x8 a2[2][10];
    #pragma unroll 1
    for (int t2 = 0; t2 < 10; ++t2) {
        const u16* w0;
        if constexpr (FIRST) {
            w0 = WLDS + (t2 * 2) * 512 + fragoff;            // all in slot0
        } else {
            if (t2 < 9)
                stage_run(W1 + (size_t)(t2 + 1) * 14 * 512,
                          WLDS + ((t2 + 1) & 1) * 14336, 14336, wave, lane);
            else {                                           // stage G2 c0 -> slot0
                stage_run(W2, WLDS, 20480, wave, lane);
                stage_run(W3, WLDS + 10240, 7168, wave, lane);
            }
            w0 = WLDS + (t2 & 1) * 14336 + fragoff;
        }
        f32x4 z = {0.f, 0.f, 0.f, 0.f};
        f32x4 ac[2][2] = {{z, z}, {z, z}};
        #pragma unroll
        for (int s = 0; s < KA; ++s) {
            s16x8 b0 = ldv(w0 + (2 * s) * 512);
            s16x8 b1 = ldv(w0 + (2 * s + 1) * 512);
            #pragma unroll
            for (int rt = 0; rt < 2; ++rt) {
                ac[rt][0] = MFMA(aF[rt][s], b0, ac[rt][0]);
                ac[rt][1] = MFMA(aF[rt][s], b1, ac[rt][1]);
            }
        }
        const int n = t2 * 32 + col;
        const float bi0 = (n < 300)      ? B1[n]      : 0.f;
        const float bi1 = (n + 16 < 300) ? B1[n + 16] : 0.f;
        #pragma unroll
        for (int rt = 0; rt < 2; ++rt)
            #pragma unroll
            for (int r = 0; r < 4; ++r) {
                int row = rt * 16 + kq * 4 + r;
                SCw[row * 40 + col]      = f2bf(fmaxf(ac[rt][0][r] + bi0, 0.f));
                SCw[row * 40 + col + 16] = f2bf(fmaxf(ac[rt][1][r] + bi1, 0.f));
            }
        #pragma unroll
        for (int rt = 0; rt < 2; ++rt)
            a2[rt][t2] = ldv(SCw + (rt * 16 + col) * 40 + kq * 8);
        if constexpr (!FIRST) __syncthreads();               // next slot ready
    }
    if constexpr (FIRST) __syncthreads();   // G1 done reading slot0 before c1 lands

    f32x4 mac[2][7];
    #pragma unroll
    for (int rt = 0; rt < 2; ++rt)
        #pragma unroll
        for (int u = 0; u < 7; ++u) { f32x4 z = {0.f, 0.f, 0.f, 0.f}; mac[rt][u] = z; }

    // ---- GEMM2 (K=320) fused with GEMM3, double-buffered slots ----
    // FIRST: chunk ch lives in slot[(ch+1)&1] (c0 staged at prologue -> slot1)
    // layer2: chunk ch lives in slot[ch&1]   (c0 staged during t2=9 -> slot0)
    constexpr int PAR = FIRST ? 1 : 0;
    #pragma unroll 1
    for (int ch = 0; ch < 10; ++ch) {
        if (ch < 9) {
            u16* dst = WLDS + (((ch + 1) + PAR) & 1) * 14336;
            stage_run(W2 + (size_t)(ch + 1) * 20 * 512, dst, 20480, wave, lane);
            stage_run(W3 + (size_t)(ch + 1) * 7 * 512, dst + 10240, 7168, wave, lane);
        }
        const u16* slot = WLDS + ((ch + PAR) & 1) * 14336;
        const u16* w0 = slot + fragoff;
        f32x4 z = {0.f, 0.f, 0.f, 0.f};
        f32x4 ac[2][2] = {{z, z}, {z, z}};
        #pragma unroll
        for (int s = 0; s < 10; ++s) {
            s16x8 b0 = ldv(w0 + (2 * s) * 512);
            s16x8 b1 = ldv(w0 + (2 * s + 1) * 512);
            #pragma unroll
            for (int rt = 0; rt < 2; ++rt) {
                ac[rt][0] = MFMA(a2[rt][s], b0, ac[rt][0]);
                ac[rt][1] = MFMA(a2[rt][s], b1, ac[rt][1]);
            }
        }
        const int n = ch * 32 + col;
        const float bi0 = (n < 300)      ? B2[n]      : 0.f;
        const float bi1 = (n + 16 < 300) ? B2[n + 16] : 0.f;
        #pragma unroll
        for (int rt = 0; rt < 2; ++rt)
            #pragma unroll
            for (int r = 0; r < 4; ++r) {
                int row = rt * 16 + kq * 4 + r;
                SCw[row * 40 + col]      = f2bf(fmaxf(ac[rt][0][r] + bi0, 0.f));
                SCw[row * 40 + col + 16] = f2bf(fmaxf(ac[rt][1][r] + bi1, 0.f));
            }
        s16x8 a3_0 = ldv(SCw + col * 40 + kq * 8);
        s16x8 a3_1 = ldv(SCw + (16 + col) * 40 + kq * 8);
        #pragma unroll
        for (int u = 0; u < 7; ++u) {
            s16x8 b3 = ldv(slot + 10240 + u * 512 + fragoff);
            mac[0][u] = MFMA(a3_0, b3, mac[0][u]);
            mac[1][u] = MFMA(a3_1, b3, mac[1][u]);
        }
        __syncthreads();
    }

    // ---- msg epilogue: fragment -> row-major [32][112] in freed weight LDS,
    //      then flat LDS->global copy (fully coalesced 1 KB stores) ----
    u16* MOUT = WLDS + wave * (32 * MS_);     // 7168 B per wave, wave-private
    #pragma unroll
    for (int rt = 0; rt < 2; ++rt)
        #pragma unroll
        for (int u = 0; u < 7; ++u) {
            int c3 = u * 16 + col;
            float bi = (c3 < 100) ? B3[c3] : 0.f;
            #pragma unroll
            for (int r = 0; r < 4; ++r) {
                int row = rt * 16 + kq * 4 + r;
                float v = (c3 < 100) ? fmaxf(mac[rt][u][r] + bi, 0.f) : 0.f;
                MOUT[row * MS_ + c3] = f2bf(v);
            }
        }
    // wave-private region: lgkmcnt ordering only
    u16* gdst = msg + (size_t)ebase * MS_;
    #pragma unroll
    for (int q = 0; q < 7; ++q) {
        s16x8 v = ldv(MOUT + q * 512 + lane * 8);
        *(s16x8*)(gdst + q * 512 + lane * 8) = v;
    }
}

// ---------------------------------------------------------------------------
// reduce_k: segment-max over sorted msg runs (stride MS_). One wave per node.
// Writes EVERY node (empty run -> 0), so agg needs no zero-init.
// ---------------------------------------------------------------------------
__global__ __launch_bounds__(256)
void reduce_k(const u16* __restrict__ msg, const int* __restrict__ pos,
              float* __restrict__ agg)
{
    const int n = blockIdx.x * 4 + (threadIdx.x >> 6);
    if (n >= N_) return;
    const int lane = threadIdx.x & 63;
    const int start = n ? pos[n - 1] : 0;
    const int end   = pos[n];
    float m0 = 0.f, m1 = 0.f;
    for (int e = start; e < end; ++e) {
        const u16* row = msg + (size_t)e * MS_;
        m0 = fmaxf(m0, bf2f(row[lane]));
        if (lane < 36) m1 = fmaxf(m1, bf2f(row[64 + lane]));
    }
    agg[(size_t)n * 100 + lane] = m0;
    if (lane < 36) agg[(size_t)n * 100 + 64 + lane] = m1;
}

// ---------------------------------------------------------------------------
// pool: one block per graph (batch sorted -> binary-search bounds).
// ---------------------------------------------------------------------------
__global__ __launch_bounds__(256)
void pool(const float* __restrict__ agg1, const int* __restrict__ batch,
          const float* __restrict__ u, float* __restrict__ pooled)
{
    const int g = blockIdx.x;
    int lo = 0, hi = N_;
    while (lo < hi) { int mid = (lo + hi) >> 1; if (batch[mid] < g) lo = mid + 1; else hi = mid; }
    const int start = lo;
    int lo2 = start, hi2 = N_;
    while (lo2 < hi2) { int mid = (lo2 + hi2) >> 1; if (batch[mid] < g + 1) lo2 = mid + 1; else hi2 = mid; }
    const int end = lo2;

    const int c = threadIdx.x & 127, half = threadIdx.x >> 7;
    float sm = 0.f, mx = 0.f;
    if (c < 100)
        for (int n = start + half; n < end; n += 2) {
            float v = agg1[(size_t)n * 100 + c];
            sm += v; mx = fmaxf(mx, v);
        }
    __shared__ float ssum[128], smax[128];
    if (half) { ssum[c] = sm; smax[c] = mx; }
    __syncthreads();
    if (!half && c < 100) {
        sm += ssum[c]; mx = fmaxf(mx, smax[c]);
        int cnt = end - start;
        pooled[g * 302 + c]       = sm;
        pooled[g * 302 + 100 + c] = sm / fmaxf((float)cnt, 1.f);
        pooled[g * 302 + 200 + c] = mx;
    }
    if (threadIdx.x == 0) {
        pooled[g * 302 + 300] = u[g * 2];
        pooled[g * 302 + 301] = u[g * 2 + 1];
    }
}

// ---------------------------------------------------------------------------
// final 302 -> 100 -> 100 -> 2 MLP, one block per graph, fp32
// ---------------------------------------------------------------------------
__global__ __launch_bounds__(128)
void final_mlp(const float* __restrict__ pooled,
               const float* __restrict__ w1, const float* __restrict__ b1,
               const float* __restrict__ w2, const float* __restrict__ b2,
               const float* __restrict__ w3, const float* __restrict__ b3,
               float* __restrict__ out)
{
    const int g = blockIdx.x, t = threadIdx.x;
    __shared__ float P[302], T1[100], T2[100];
    for (int i = t; i < 302; i += 128) P[i] = pooled[g * 302 + i];
    __syncthreads();
    if (t < 100) {
        float a = b1[t];
        for (int i = 0; i < 302; ++i) a = fmaf(P[i], w1[i * 100 + t], a);
        T1[t] = fmaxf(a, 0.f);
    }
    __syncthreads();
    if (t < 100) {
        float a = b2[t];
        for (int i = 0; i < 100; ++i) a = fmaf(T1[i], w2[i * 100 + t], a);
        T2[t] = fmaxf(a, 0.f);
    }
    __syncthreads();
    if (t < 2) {
        float a = b3[t];
        for (int i = 0; i < 100; ++i) a = fmaf(T2[i], w3[i * 2 + t], a);
        out[g * 2 + t] = a;
    }
}

// ---------------------------------------------------------------------------
extern "C" void kernel_launch(void* const* d_in, const int* in_sizes, int n_in,
                              void* d_out, int out_size, void* d_ws, size_t ws_size,
                              hipStream_t stream)
{
    const float* x     = (const float*)d_in[0];
    const int*   ei    = (const int*)d_in[1];
    const int*   batch = (const int*)d_in[2];
    const float* uu    = (const float*)d_in[3];
    const float *l0w1 = (const float*)d_in[4],  *l0b1 = (const float*)d_in[5];
    const float *l0w2 = (const float*)d_in[6],  *l0b2 = (const float*)d_in[7];
    const float *l0w3 = (const float*)d_in[8],  *l0b3 = (const float*)d_in[9];
    const float *l1w1 = (const float*)d_in[10], *l1b1 = (const float*)d_in[11];
    const float *l1w2 = (const float*)d_in[12], *l1b2 = (const float*)d_in[13];
    const float *l1w3 = (const float*)d_in[14], *l1b3 = (const float*)d_in[15];
    const float *lw1  = (const float*)d_in[16], *lb1  = (const float*)d_in[17];
    const float *lw2  = (const float*)d_in[18], *lb2  = (const float*)d_in[19];
    const float *lw3  = (const float*)d_in[20], *lb3  = (const float*)d_in[21];

    char* w = (char*)d_ws;
    float* agg0   = (float*)(w);                    // 20,000,000 B
    float* agg1   = (float*)(w + 20000000);         // 20,000,000 B
    float* pooled = (float*)(w + 40000000);         //     77,312 B
    u16* wt0  = (u16*)(w + 40077312);               //     20,480 B
    u16* wt1  = (u16*)(w + 40097792);               //    143,360 B
    u16* wt2a = (u16*)(w + 40241152);               //    204,800 B
    u16* wt2b = (u16*)(w + 40445952);               //    204,800 B
    u16* wt3a = (u16*)(w + 40650752);               //     71,680 B
    u16* wt3b = (u16*)(w + 40722432);               //     71,680 B
    int* hist = (int*)(w + 40794112);               //    200,000 B (hist -> run ends)
    int* sei  = (int*)(w + 40994112);               //  3,200,000 B (sorted [src|dst])
    u16* msg  = (u16*)(w + 44194112);               // 89,600,000 B (msgs, 224 B rows)
                                                    // total ~127.6 MiB

    ModelGNN_35304631174019_kernel<<<1449, 256, 0, stream>>>(
        l0w1, l0w2, l0w3, l1w1, l1w2, l1w3,
        (float4*)hist, wt0, wt1, wt2a, wt2b, wt3a, wt3b);
    hist_k<<<1563, 256, 0, stream>>>(ei, hist);
    scan_k<<<1, 1024, 0, stream>>>(hist);
    fill_k<<<1563, 256, 0, stream>>>(ei, hist, sei);
    edge_mlp<true ><<<3125, 256, 0, stream>>>(x, nullptr, sei, wt0, l0b1, wt2a, l0b2, wt3a, l0b3, msg);
    reduce_k<<<12500, 256, 0, stream>>>(msg, hist, agg0);
    edge_mlp<false><<<3125, 256, 0, stream>>>(nullptr, agg0, sei, wt1, l1b1, wt2b, l1b2, wt3b, l1b3, msg);
    reduce_k<<<12500, 256, 0, stream>>>(msg, hist, agg1);
    pool<<<G_, 256, 0, stream>>>(agg1, batch, uu, pooled);
    final_mlp<<<G_, 128, 0, stream>>>(pooled, lw1, lb1, lw2, lb2, lw3, lb3, (float*)d_out);
}

// Round 7
// 1366.559 us; speedup vs baseline: 1.1777x; 1.1777x over previous
//
#include <hip/hip_runtime.h>

typedef unsigned short u16;
typedef short s16x8 __attribute__((ext_vector_type(8)));   // 8 bf16 bit-patterns
typedef float f32x4 __attribute__((ext_vector_type(4)));

#define DI __device__ __forceinline__

constexpr int N_ = 50000;
constexpr int E_ = 400000;
constexpr int G_ = 64;
constexpr int MS_ = 112;            // msg row stride in u16 (224 B)

DI u16 f2bf(float f) {
    union { unsigned u; float f; } c; c.f = f;
    unsigned u = c.u;
    u += 0x7fffu + ((u >> 16) & 1u);   // RNE
    return (u16)(u >> 16);
}
DI float bf2f(u16 v) {
    union { unsigned u; float f; } c; c.u = (unsigned)v << 16;
    return c.f;
}
DI unsigned pkbf(float lo, float hi) {   // u32 = bf16(lo) | bf16(hi)<<16 (RNE)
    return (unsigned)f2bf(lo) | ((unsigned)f2bf(hi) << 16);
}

DI s16x8 ldv(const u16* p) { return *(const s16x8*)p; }
DI f32x4 MFMA(s16x8 a, s16x8 b, f32x4 c) {
    return __builtin_amdgcn_mfma_f32_16x16x32_bf16(a, b, c, 0, 0, 0);
}

// ---------------------------------------------------------------------------
// C-frag pair (transposed GEMM output: rows=channels, cols=edges) -> next
// GEMM's B-frag (lane&15=edge, k=kq*8+j), fused ReLU. Source lane (col,kq)
// holds H[ch=cb*16+kq*4+r][edge=col]; target lane (col',kq') needs channels
// kq'*8+j of edge col'. 8 pkbf + 8 ds_bpermute + 4 selects, no LDS storage.
// Verified case-by-case against C/D layout col=lane&15,row=kq*4+r (m89).
// ---------------------------------------------------------------------------
DI s16x8 conv_frag(const f32x4 a0, const f32x4 a1, int kq, int col) {
    unsigned c0 = pkbf(fmaxf(a0[0], 0.f), fmaxf(a0[1], 0.f));
    unsigned c1 = pkbf(fmaxf(a0[2], 0.f), fmaxf(a0[3], 0.f));
    unsigned c2 = pkbf(fmaxf(a1[0], 0.f), fmaxf(a1[1], 0.f));
    unsigned c3 = pkbf(fmaxf(a1[2], 0.f), fmaxf(a1[3], 0.f));
    int aA = (kq & 1) * 128 + col * 4;       // src lane (kq&1)*32 + col
    int aB = aA + 64;                        // src lane (kq&1)*32 + 16 + col
    unsigned A0 = __builtin_amdgcn_ds_bpermute(aA, (int)c0);
    unsigned A1 = __builtin_amdgcn_ds_bpermute(aA, (int)c1);
    unsigned A2 = __builtin_amdgcn_ds_bpermute(aA, (int)c2);
    unsigned A3 = __builtin_amdgcn_ds_bpermute(aA, (int)c3);
    unsigned B0 = __builtin_amdgcn_ds_bpermute(aB, (int)c0);
    unsigned B1 = __builtin_amdgcn_ds_bpermute(aB, (int)c1);
    unsigned B2 = __builtin_amdgcn_ds_bpermute(aB, (int)c2);
    unsigned B3 = __builtin_amdgcn_ds_bpermute(aB, (int)c3);
    bool hi = (kq >> 1) != 0;
    union { unsigned u[4]; s16x8 v; } o;
    o.u[0] = hi ? A2 : A0;
    o.u[1] = hi ? A3 : A1;
    o.u[2] = hi ? B2 : B0;
    o.u[3] = hi ? B3 : B1;
    return o.v;
}

// ---------------------------------------------------------------------------
// Named kernel (symbol required by harness): zero hist (200 KB) and repack
// weights f32 -> bf16 in MFMA-FRAGMENT-ORDER TILES, folding
//   [xi, xj-xi] @ W = xi @ (W_a - W_b) + xj @ W_b,
// and folding BIASES into unused K-pad rows (input slot := 1.0):
//   wt0 k=15 := B1 ; wt1 k=100 := B1 ; wt2 k=300 := B2 ; wt3 k=300 := B3.
// ---------------------------------------------------------------------------
__global__ __launch_bounds__(256)
void ModelGNN_35304631174019_kernel(
          const float* __restrict__ l0w1, const float* __restrict__ l0w2,
          const float* __restrict__ l0w3, const float* __restrict__ l1w1,
          const float* __restrict__ l1w2, const float* __restrict__ l1w3,
          const float* __restrict__ l0b1, const float* __restrict__ l0b2,
          const float* __restrict__ l0b3, const float* __restrict__ l1b1,
          const float* __restrict__ l1b2, const float* __restrict__ l1b3,
          float4* __restrict__ histz,
          u16* __restrict__ wt0, u16* __restrict__ wt1,
          u16* __restrict__ wt2a, u16* __restrict__ wt2b,
          u16* __restrict__ wt3a, u16* __restrict__ wt3b)
{
    int i = blockIdx.x * 256 + threadIdx.x;
    if (i < 12500) { histz[i] = make_float4(0.f, 0.f, 0.f, 0.f); return; }
    int f = i - 12500;

    if (f < 10240) {                       // wt0: layer0 W1, KP=32 (KA=1)
        int sec = f >> 9, w = f & 511;
        int col = w >> 5, rem = w & 31;
        int n0c = sec >> 1, b01 = sec & 1;
        int n = n0c * 32 + b01 * 16 + col, k = rem;
        u16 v = 0;
        if (n < 300) {
            if (k < 7)                  v = f2bf(l0w1[k * 300 + n] - l0w1[(7 + k) * 300 + n]);
            else if (k >= 16 && k < 23) v = f2bf(l0w1[(7 + (k - 16)) * 300 + n]);
            else if (k == 15)           v = f2bf(l0b1[n]);
        }
        wt0[f] = v; return;
    }
    f -= 10240;
    if (f < 71680) {                       // wt1: layer1 W1, KP=224 (KA=7)
        int sec = f >> 9, w = f & 511;
        int col = w >> 5, rem = w & 31;
        int n0c = sec / 14, r = sec % 14;
        int s = r >> 1, b01 = r & 1;
        int n = n0c * 32 + b01 * 16 + col, k = s * 32 + rem;
        u16 v = 0;
        if (n < 300) {
            if (k < 100)                  v = f2bf(l1w1[k * 300 + n] - l1w1[(100 + k) * 300 + n]);
            else if (k >= 112 && k < 212) v = f2bf(l1w1[(100 + (k - 112)) * 300 + n]);
            else if (k == 100)            v = f2bf(l1b1[n]);
        }
        wt1[f] = v; return;
    }
    f -= 71680;
    if (f < 204800) {                      // wt2a / wt2b: 300x300, K=320 (KA=10)
        const float* src = (f < 102400) ? l0w2 : l1w2;
        const float* bia = (f < 102400) ? l0b2 : l1b2;
        u16* dst = (f < 102400) ? wt2a : wt2b;
        int f2 = (f < 102400) ? f : f - 102400;
        int sec = f2 >> 9, w = f2 & 511;
        int col = w >> 5, rem = w & 31;
        int n0c = sec / 20, r = sec % 20;
        int s = r >> 1, b01 = r & 1;
        int n = n0c * 32 + b01 * 16 + col, k = s * 32 + rem;
        u16 v = 0;
        if (n < 300) {
            if (k < 300)       v = f2bf(src[k * 300 + n]);
            else if (k == 300) v = f2bf(bia[n]);
        }
        dst[f2] = v;
        return;
    }
    f -= 204800;
    if (f < 71680) {                       // wt3a / wt3b: 300x100 -> [112 n3][320 k]
        const float* src = (f < 35840) ? l0w3 : l1w3;
        const float* bia = (f < 35840) ? l0b3 : l1b3;
        u16* dst = (f < 35840) ? wt3a : wt3b;
        int f2 = (f < 35840) ? f : f - 35840;
        int sec = f2 >> 9, w = f2 & 511;
        int col = w >> 5, rem = w & 31;
        int ch = sec / 7, u = sec % 7;
        int n3 = u * 16 + col, k = ch * 32 + rem;
        u16 v = 0;
        if (n3 < 100) {
            if (k < 300)       v = f2bf(src[k * 100 + n3]);
            else if (k == 300) v = f2bf(bia[n3]);
        }
        dst[f2] = v;
        return;
    }
}

// ---------------------------------------------------------------------------
// Count-sort edges by dst: hist -> exclusive scan -> scatter-fill.
// pos[d] = run END after fill (start = pos[d-1] or 0) -- used by reduce_k.
// ---------------------------------------------------------------------------
__global__ __launch_bounds__(256)
void hist_k(const int* __restrict__ ei, int* __restrict__ hist)
{
    int i = blockIdx.x * 256 + threadIdx.x;
    if (i < E_) atomicAdd(&hist[ei[E_ + i]], 1);
}

__global__ __launch_bounds__(1024)
void scan_k(int* h)   // in-place exclusive scan of h[50000], single block
{
    __shared__ int part[1024];
    const int t = threadIdx.x;
    const int CH = 49;
    int base = t * CH;
    int end = base + CH; if (end > 50000) end = 50000;
    int s = 0;
    for (int i = base; i < end; ++i) s += h[i];
    part[t] = s;
    __syncthreads();
    for (int d = 1; d < 1024; d <<= 1) {
        int v = (t >= d) ? part[t - d] : 0;
        __syncthreads();
        part[t] += v;
        __syncthreads();
    }
    int run = (t ? part[t - 1] : 0);
    for (int i = base; i < end; ++i) { int c = h[i]; h[i] = run; run += c; }
}

__global__ __launch_bounds__(256)
void fill_k(const int* __restrict__ ei, int* __restrict__ pos, int* __restrict__ sei)
{
    int i = blockIdx.x * 256 + threadIdx.x;
    if (i >= E_) return;
    int s = ei[i], d = ei[E_ + i];
    int p = atomicAdd(&pos[d], 1);
    sei[p] = s; sei[E_ + p] = d;
}

// ---------------------------------------------------------------------------
// edge_mlp R16 (= R15 minus inline asm): OPERAND-SWAPPED MFMA pipeline --
// zero LDS transit in loops. R0-R4 invariant: ~530us regardless of
// scatter/occupancy/staging; the untouched common element was 30 per-chunk
// LDS write->lgkm->read transits in the GEMM1->2->3 dataflow. Fix:
// MFMA(W,X) instead of MFMA(X,W) puts channels in C-rows / edges in
// C-cols; C->next-B conversion is then pkbf + 8 ds_bpermute per fragment
// (conv_frag), fully in-register. Biases folded into weight K-pad rows
// (input slot := 1.0), so chunks are pure {load 2 frags -> 4 MFMA} chains.
// Single LDS use: epilogue repack for coalesced 224B-row msg stores.
// No atomics (sorted msg + reduce_k).
// Layouts (m89/m120): A/B: row=lane&15, k=kq*8+j ; C/D: col=lane&15,
// row=kq*4+r (here row=channel, col=edge).
// ---------------------------------------------------------------------------
template<bool FIRST>
__global__ __launch_bounds__(256, 1)
void edge_mlp(const float* __restrict__ X, const float* __restrict__ H0,
              const int* __restrict__ ei,
              const u16* __restrict__ W1, const u16* __restrict__ W2,
              const u16* __restrict__ W3,
              u16* __restrict__ msg)
{
    constexpr int KP = FIRST ? 32 : 224;
    constexpr int KA = KP / 32;
    __shared__ __align__(16) u16 SCR[4 * 32 * MS_];   // 28,672 B (epilogue/gather)

    const int tid  = threadIdx.x;
    const int wave = tid >> 6, lane = tid & 63;
    const int col  = lane & 15, kq = lane >> 4;
    const int ebase = blockIdx.x * 128 + wave * 32;   // 32 edges per wave
    const int fragoff = col * 32 + kq * 8;            // in-section lane offset

    u16* SCw = SCR + wave * (32 * MS_);

    // ---- input fragments (edges as B-operand: row=edge, k=input dim) ----
    s16x8 aF[2][KA];
    if constexpr (FIRST) {
        // gather [xi | 1 | xj] for 32 edges into SCw as bf16 IN[32][40]
        for (int s = lane; s < 32 * 32; s += 64) {
            int e = s >> 5, k = s & 31;
            u16 v = 0;
            if (k < 7)                  v = f2bf(X[(size_t)ei[E_ + ebase + e] * 7 + k]);
            else if (k >= 16 && k < 23) v = f2bf(X[(size_t)ei[ebase + e] * 7 + (k - 16)]);
            else if (k == 15)           v = 0x3f80;   // bias slot: 1.0
            SCw[e * 40 + k] = v;
        }
        #pragma unroll
        for (int rt = 0; rt < 2; ++rt)
            aF[rt][0] = ldv(SCw + (rt * 16 + col) * 40 + kq * 8);
    } else {
        // build fragments from global agg0 (h0, f32 -> bf16), 2 row-tiles
        #pragma unroll
        for (int rt = 0; rt < 2; ++rt) {
            const int dn = ei[E_ + ebase + rt * 16 + col];   // x_i
            const int sn = ei[ebase + rt * 16 + col];        // x_j
            #pragma unroll
            for (int s = 0; s < KA; ++s) {
                int b = s * 4 + kq;                // 8-elem k-group; k = 8b+j
                int node = (b < 14) ? dn : sn;
                int c = ((b < 14) ? b : b - 14) * 8;
                s16x8 t = {0, 0, 0, 0, 0, 0, 0, 0};
                if (c < 104) {
                    const float* r = H0 + (size_t)node * 100 + c;
                    float4 lo = *(const float4*)r;
                    t[0] = (short)f2bf(lo.x); t[1] = (short)f2bf(lo.y);
                    t[2] = (short)f2bf(lo.z); t[3] = (short)f2bf(lo.w);
                    if (c < 96) {
                        float4 hi = *(const float4*)(r + 4);
                        t[4] = (short)f2bf(hi.x); t[5] = (short)f2bf(hi.y);
                        t[6] = (short)f2bf(hi.z); t[7] = (short)f2bf(hi.w);
                    }
                }
                if (s == 3 && kq == 0) t[4] = (short)0x3f80;  // k=100 bias slot
                aF[rt][s] = t;
            }
        }
    }

    // ---- GEMM1: H1^T chunks -> in-register conv -> a2 B-fragments ----
    s16x8 a2[2][10];
    #pragma unroll 1
    for (int t2 = 0; t2 < 10; ++t2) {
        const u16* w0 = W1 + (size_t)(t2 * 2 * KA) * 512 + fragoff;
        f32x4 z = {0.f, 0.f, 0.f, 0.f};
        f32x4 ac[2][2] = {{z, z}, {z, z}};            // [cb(ch-half)][rt(edge-half)]
        #pragma unroll
        for (int s = 0; s < KA; ++s) {
            s16x8 b0 = ldv(w0 + (2 * s) * 512);       // contiguous 1 KB wave-load
            s16x8 b1 = ldv(w0 + (2 * s + 1) * 512);
            #pragma unroll
            for (int rt = 0; rt < 2; ++rt) {
                ac[0][rt] = MFMA(b0, aF[rt][s], ac[0][rt]);
                ac[1][rt] = MFMA(b1, aF[rt][s], ac[1][rt]);
            }
        }
        #pragma unroll
        for (int rt = 0; rt < 2; ++rt)
            a2[rt][t2] = conv_frag(ac[0][rt], ac[1][rt], kq, col);
    }
    if (kq == 1) {                                    // GEMM2 k=300 bias slot
        a2[0][9][4] = (short)0x3f80;
        a2[1][9][4] = (short)0x3f80;
    }

    f32x4 mac[2][7];
    #pragma unroll
    for (int rt = 0; rt < 2; ++rt)
        #pragma unroll
        for (int u = 0; u < 7; ++u) { f32x4 z = {0.f, 0.f, 0.f, 0.f}; mac[rt][u] = z; }

    // ---- GEMM2 (K=320) fused with GEMM3 in 32-wide chunks of H2 ----
    #pragma unroll 1
    for (int ch = 0; ch < 10; ++ch) {
        const u16* w0 = W2 + (size_t)(ch * 20) * 512 + fragoff;
        f32x4 z = {0.f, 0.f, 0.f, 0.f};
        f32x4 ac[2][2] = {{z, z}, {z, z}};
        #pragma unroll
        for (int s = 0; s < 10; ++s) {
            s16x8 b0 = ldv(w0 + (2 * s) * 512);       // contiguous 1 KB wave-load
            s16x8 b1 = ldv(w0 + (2 * s + 1) * 512);
            #pragma unroll
            for (int rt = 0; rt < 2; ++rt) {
                ac[0][rt] = MFMA(b0, a2[rt][s], ac[0][rt]);
                ac[1][rt] = MFMA(b1, a2[rt][s], ac[1][rt]);
            }
        }
        s16x8 a3[2];
        #pragma unroll
        for (int rt = 0; rt < 2; ++rt)
            a3[rt] = conv_frag(ac[0][rt], ac[1][rt], kq, col);
        if (ch == 9 && kq == 1) {                     // GEMM3 k=300 bias slot
            a3[0][4] = (short)0x3f80;
            a3[1][4] = (short)0x3f80;
        }
        #pragma unroll
        for (int u = 0; u < 7; ++u) {
            s16x8 b3 = ldv(W3 + (size_t)(ch * 7 + u) * 512 + fragoff);  // 1 KB
            mac[0][u] = MFMA(b3, a3[0], mac[0][u]);
            mac[1][u] = MFMA(b3, a3[1], mac[1][u]);
        }
    }

    // ---- epilogue: mac rows=out-channels, cols=edges. Pack relu'd pairs to
    //      LDS [32 edges][112 ch], then coalesced 16B-lane global stores ----
    #pragma unroll
    for (int rt = 0; rt < 2; ++rt) {
        const int row = rt * 16 + col;
        #pragma unroll
        for (int u = 0; u < 7; ++u) {
            unsigned p0 = pkbf(fmaxf(mac[rt][u][0], 0.f), fmaxf(mac[rt][u][1], 0.f));
            unsigned p1 = pkbf(fmaxf(mac[rt][u][2], 0.f), fmaxf(mac[rt][u][3], 0.f));
            int chb = u * 16 + kq * 4;
            *(unsigned*)(SCw + row * MS_ + chb)     = p0;
            *(unsigned*)(SCw + row * MS_ + chb + 2) = p1;
        }
    }
    // wave-private region: lgkmcnt ordering only
    u16* gdst = msg + (size_t)ebase * MS_;
    #pragma unroll
    for (int q = 0; q < 7; ++q) {
        s16x8 v = ldv(SCw + q * 512 + lane * 8);
        *(s16x8*)(gdst + q * 512 + lane * 8) = v;
    }
}

// ---------------------------------------------------------------------------
// reduce_k: segment-max over sorted msg runs (stride MS_). One wave per node.
// Writes EVERY node (empty run -> 0), so agg needs no zero-init.
// ---------------------------------------------------------------------------
__global__ __launch_bounds__(256)
void reduce_k(const u16* __restrict__ msg, const int* __restrict__ pos,
              float* __restrict__ agg)
{
    const int n = blockIdx.x * 4 + (threadIdx.x >> 6);
    if (n >= N_) return;
    const int lane = threadIdx.x & 63;
    const int start = n ? pos[n - 1] : 0;
    const int end   = pos[n];
    float m0 = 0.f, m1 = 0.f;
    for (int e = start; e < end; ++e) {
        const u16* row = msg + (size_t)e * MS_;
        m0 = fmaxf(m0, bf2f(row[lane]));
        if (lane < 36) m1 = fmaxf(m1, bf2f(row[64 + lane]));
    }
    agg[(size_t)n * 100 + lane] = m0;
    if (lane < 36) agg[(size_t)n * 100 + 64 + lane] = m1;
}

// ---------------------------------------------------------------------------
// pool: one block per graph (batch sorted -> binary-search bounds).
// ---------------------------------------------------------------------------
__global__ __launch_bounds__(256)
void pool(const float* __restrict__ agg1, const int* __restrict__ batch,
          const float* __restrict__ u, float* __restrict__ pooled)
{
    const int g = blockIdx.x;
    int lo = 0, hi = N_;
    while (lo < hi) { int mid = (lo + hi) >> 1; if (batch[mid] < g) lo = mid + 1; else hi = mid; }
    const int start = lo;
    int lo2 = start, hi2 = N_;
    while (lo2 < hi2) { int mid = (lo2 + hi2) >> 1; if (batch[mid] < g + 1) lo2 = mid + 1; else hi2 = mid; }
    const int end = lo2;

    const int c = threadIdx.x & 127, half = threadIdx.x >> 7;
    float sm = 0.f, mx = 0.f;
    if (c < 100)
        for (int n = start + half; n < end; n += 2) {
            float v = agg1[(size_t)n * 100 + c];
            sm += v; mx = fmaxf(mx, v);
        }
    __shared__ float ssum[128], smax[128];
    if (half) { ssum[c] = sm; smax[c] = mx; }
    __syncthreads();
    if (!half && c < 100) {
        sm += ssum[c]; mx = fmaxf(mx, smax[c]);
        int cnt = end - start;
        pooled[g * 302 + c]       = sm;
        pooled[g * 302 + 100 + c] = sm / fmaxf((float)cnt, 1.f);
        pooled[g * 302 + 200 + c] = mx;
    }
    if (threadIdx.x == 0) {
        pooled[g * 302 + 300] = u[g * 2];
        pooled[g * 302 + 301] = u[g * 2 + 1];
    }
}

// ---------------------------------------------------------------------------
// final 302 -> 100 -> 100 -> 2 MLP, one block per graph, fp32
// ---------------------------------------------------------------------------
__global__ __launch_bounds__(128)
void final_mlp(const float* __restrict__ pooled,
               const float* __restrict__ w1, const float* __restrict__ b1,
               const float* __restrict__ w2, const float* __restrict__ b2,
               const float* __restrict__ w3, const float* __restrict__ b3,
               float* __restrict__ out)
{
    const int g = blockIdx.x, t = threadIdx.x;
    __shared__ float P[302], T1[100], T2[100];
    for (int i = t; i < 302; i += 128) P[i] = pooled[g * 302 + i];
    __syncthreads();
    if (t < 100) {
        float a = b1[t];
        for (int i = 0; i < 302; ++i) a = fmaf(P[i], w1[i * 100 + t], a);
        T1[t] = fmaxf(a, 0.f);
    }
    __syncthreads();
    if (t < 100) {
        float a = b2[t];
        for (int i = 0; i < 100; ++i) a = fmaf(T1[i], w2[i * 100 + t], a);
        T2[t] = fmaxf(a, 0.f);
    }
    __syncthreads();
    if (t < 2) {
        float a = b3[t];
        for (int i = 0; i < 100; ++i) a = fmaf(T2[i], w3[i * 2 + t], a);
        out[g * 2 + t] = a;
    }
}

// ---------------------------------------------------------------------------
extern "C" void kernel_launch(void* const* d_in, const int* in_sizes, int n_in,
                              void* d_out, int out_size, void* d_ws, size_t ws_size,
                              hipStream_t stream)
{
    const float* x     = (const float*)d_in[0];
    const int*   ei    = (const int*)d_in[1];
    const int*   batch = (const int*)d_in[2];
    const float* uu    = (const float*)d_in[3];
    const float *l0w1 = (const float*)d_in[4],  *l0b1 = (const float*)d_in[5];
    const float *l0w2 = (const float*)d_in[6],  *l0b2 = (const float*)d_in[7];
    const float *l0w3 = (const float*)d_in[8],  *l0b3 = (const float*)d_in[9];
    const float *l1w1 = (const float*)d_in[10], *l1b1 = (const float*)d_in[11];
    const float *l1w2 = (const float*)d_in[12], *l1b2 = (const float*)d_in[13];
    const float *l1w3 = (const float*)d_in[14], *l1b3 = (const float*)d_in[15];
    const float *lw1  = (const float*)d_in[16], *lb1  = (const float*)d_in[17];
    const float *lw2  = (const float*)d_in[18], *lb2  = (const float*)d_in[19];
    const float *lw3  = (const float*)d_in[20], *lb3  = (const float*)d_in[21];

    char* w = (char*)d_ws;
    float* agg0   = (float*)(w);                    // 20,000,000 B
    float* agg1   = (float*)(w + 20000000);         // 20,000,000 B
    float* pooled = (float*)(w + 40000000);         //     77,312 B
    u16* wt0  = (u16*)(w + 40077312);               //     20,480 B
    u16* wt1  = (u16*)(w + 40097792);               //    143,360 B
    u16* wt2a = (u16*)(w + 40241152);               //    204,800 B
    u16* wt2b = (u16*)(w + 40445952);               //    204,800 B
    u16* wt3a = (u16*)(w + 40650752);               //     71,680 B
    u16* wt3b = (u16*)(w + 40722432);               //     71,680 B
    int* hist = (int*)(w + 40794112);               //    200,000 B (hist -> run ends)
    int* sei  = (int*)(w + 40994112);               //  3,200,000 B (sorted [src|dst])
    u16* msg  = (u16*)(w + 44194112);               // 89,600,000 B (msgs, 224 B rows)
                                                    // total ~127.6 MiB

    ModelGNN_35304631174019_kernel<<<1449, 256, 0, stream>>>(
        l0w1, l0w2, l0w3, l1w1, l1w2, l1w3,
        l0b1, l0b2, l0b3, l1b1, l1b2, l1b3,
        (float4*)hist, wt0, wt1, wt2a, wt2b, wt3a, wt3b);
    hist_k<<<1563, 256, 0, stream>>>(ei, hist);
    scan_k<<<1, 1024, 0, stream>>>(hist);
    fill_k<<<1563, 256, 0, stream>>>(ei, hist, sei);
    edge_mlp<true ><<<3125, 256, 0, stream>>>(x, nullptr, sei, wt0, wt2a, wt3a, msg);
    reduce_k<<<12500, 256, 0, stream>>>(msg, hist, agg0);
    edge_mlp<false><<<3125, 256, 0, stream>>>(nullptr, agg0, sei, wt1, wt2b, wt3b, msg);
    reduce_k<<<12500, 256, 0, stream>>>(msg, hist, agg1);
    pool<<<G_, 256, 0, stream>>>(agg1, batch, uu, pooled);
    final_mlp<<<G_, 128, 0, stream>>>(pooled, lw1, lb1, lw2, lb2, lw3, lb3, (float*)d_out);
}